// Round 1
// baseline (4570.115 us; speedup 1.0000x reference)
//
#include <hip/hip_runtime.h>
#include <stdint.h>

// ---------------- problem constants ----------------
#define T_STEPS 1000
#define B_SZ    32
#define NI      512
#define NH      1024
#define NO      256

// R7 scan decomposition: block (jg, bg) owns j in [32*jg, 32*jg+32) for the
// 4 batches [4*bg, 4*bg+4).  256 blocks, 1 per CU, all co-resident (required
// for the per-step all-to-all).  W columns for the block's 32 j's live in LDS
// (132 KB), so the per-step recurrent gather does ZERO L2/global traffic --
// R6 burned ~1.2 us/step of per-XCD L2 BW on 32x-duplicated WTS re-reads.
#define JBLK    32
#define BBATCH  4
#define NJG     (NH / JBLK)       // 32
#define NBG     (B_SZ / BBATCH)   // 8
#define NBLK    (NJG * NBG)       // 256

typedef unsigned long long u64;

// ---------------- ws layout (bytes) ----------------
#define OFF_IEXT 0ull
#define SZ_IEXT  ((u64)T_STEPS * B_SZ * NH * 4ull)   // 131,072,000
#define OFF_RATE (OFF_IEXT + SZ_IEXT)
#define SZ_RATE  ((u64)B_SZ * NH * 4ull)             // 128 KiB
#define OFF_SYNC (OFF_RATE + SZ_RATE)
#define SZ_SYNC  ((u64)2 * B_SZ * NJG * 8ull)        // 16 KiB: [par][b][chunk] tagged u64

// ---------------- agent-scope helpers ----------------
__device__ __forceinline__ u64 ld64_agent(const u64* p) {
  return __hip_atomic_load(p, __ATOMIC_RELAXED, __HIP_MEMORY_SCOPE_AGENT);
}
__device__ __forceinline__ void st64_agent(u64* p, u64 v) {
  __hip_atomic_store(p, v, __ATOMIC_RELAXED, __HIP_MEMORY_SCOPE_AGENT);
}

// ---------------- kernel 1: I_ext = x @ W_in^T  (fp32 tiled, unchanged) ----------------
// Kept fp32: bf16 I_ext would flip threshold crossings and cascade.
#define GBM 128
#define GBN 128
#define GBK 16
__global__ __launch_bounds__(256) void gemm_in(const float* __restrict__ X,
                                               const float* __restrict__ Win,
                                               float* __restrict__ I) {
  __shared__ float As[GBK][GBM + 4];
  __shared__ float Bs[GBK][GBN + 4];
  const int tid = threadIdx.x;
  const int m0 = blockIdx.x * GBM;
  const int n0 = blockIdx.y * GBN;
  const int tm = tid >> 4, tn = tid & 15;
  const int lr = tid >> 1, lk = (tid & 1) * 8;
  float acc[8][8] = {};
  for (int k0 = 0; k0 < NI; k0 += GBK) {
    float4 a0 = *(const float4*)&X[(size_t)(m0 + lr) * NI + k0 + lk];
    float4 a1 = *(const float4*)&X[(size_t)(m0 + lr) * NI + k0 + lk + 4];
    float4 b0 = *(const float4*)&Win[(size_t)(n0 + lr) * NI + k0 + lk];
    float4 b1 = *(const float4*)&Win[(size_t)(n0 + lr) * NI + k0 + lk + 4];
    As[lk + 0][lr] = a0.x; As[lk + 1][lr] = a0.y; As[lk + 2][lr] = a0.z; As[lk + 3][lr] = a0.w;
    As[lk + 4][lr] = a1.x; As[lk + 5][lr] = a1.y; As[lk + 6][lr] = a1.z; As[lk + 7][lr] = a1.w;
    Bs[lk + 0][lr] = b0.x; Bs[lk + 1][lr] = b0.y; Bs[lk + 2][lr] = b0.z; Bs[lk + 3][lr] = b0.w;
    Bs[lk + 4][lr] = b1.x; Bs[lk + 5][lr] = b1.y; Bs[lk + 6][lr] = b1.z; Bs[lk + 7][lr] = b1.w;
    __syncthreads();
#pragma unroll
    for (int k = 0; k < GBK; ++k) {
      float av[8], bv[8];
      *(float4*)&av[0] = *(const float4*)&As[k][tm * 8];
      *(float4*)&av[4] = *(const float4*)&As[k][tm * 8 + 4];
      *(float4*)&bv[0] = *(const float4*)&Bs[k][tn * 8];
      *(float4*)&bv[4] = *(const float4*)&Bs[k][tn * 8 + 4];
#pragma unroll
      for (int i2 = 0; i2 < 8; ++i2)
#pragma unroll
        for (int j2 = 0; j2 < 8; ++j2) acc[i2][j2] += av[i2] * bv[j2];
    }
    __syncthreads();
  }
#pragma unroll
  for (int i2 = 0; i2 < 8; ++i2) {
    float4 c0 = {acc[i2][0], acc[i2][1], acc[i2][2], acc[i2][3]};
    float4 c1 = {acc[i2][4], acc[i2][5], acc[i2][6], acc[i2][7]};
    *(float4*)&I[(size_t)(m0 + tm * 8 + i2) * NH + n0 + tn * 8] = c0;
    *(float4*)&I[(size_t)(m0 + tm * 8 + i2) * NH + n0 + tn * 8 + 4] = c1;
  }
}

// ---------------- kernel 2: persistent 1000-step scan, j-split x batch-group ----------------
// FP-trajectory identical to R6: per (b,j), rec = [left-fold of spiked i<512,
// ascending] + [left-fold of spiked i>=512, ascending] -- exactly R6's A-half
// (words 0-15) + B-half (words 16-31) association.  State-update op order is
// copied verbatim.  Sync format (32-bit payload | (t+1)<<32 per u64, parity
// double-buffer, 0xAA poison never matching, deterministic-rerun tag collision
// at t=998 benign) is carried over from R6; communication groups are the 32
// blocks sharing a bg (closed, so the t/t+2 slot-overwrite safety proof holds).
__global__ __launch_bounds__(256) void scan_rsnn(const float* __restrict__ Iext,
                                                 const float* __restrict__ Wrec,
                                                 float* __restrict__ rate,
                                                 u64* sync) {
  __shared__ float WL[NH][JBLK + 1];            // WL[i][jl] = Wrec[j0+jl][i]; stride 33 -> 2-way banks (free)
  __shared__ unsigned short slist[BBATCH][NH];  // per-batch spiked-i list, i-ascending
  __shared__ int scnt[BBATCH][2];               // [0]=cntA (i<512), [1]=cnt
  __shared__ float psumB[128];                  // hi-half partial sums

  const int bid = blockIdx.x;
  const int jg  = bid & (NJG - 1);
  const int bg  = bid >> 5;
  const int j0  = jg * JBLK;
  const int b0  = bg * BBATCH;
  const int tid = threadIdx.x;
  const int wv  = tid >> 6;
  const int ln  = tid & 63;
  const int bl  = (tid >> 5) & 3;   // batch-local (state / poll / gather)
  const int jl  = tid & 31;         // j-local; doubles as chunk index c for the poll

  // ---- one-time: stage W columns into LDS (coalesced reads, stride-1 lane writes) ----
  for (int k = 0; k < 128; ++k) {
    const int jj = k >> 2;
    const int i  = ((k & 3) << 8) | tid;
    WL[i][jj] = Wrec[(size_t)(j0 + jj) * NH + i];
  }

  const float D1 = 0.90483741803595957f;  // exp(-0.1)
  const float D2 = 0.81873075307798186f;  // exp(-0.2) == decay_syn

  float v = -60.0f, A1 = 0.0f, A2 = 0.0f, rf = 0.0f, h = 0.0f, psc = 0.0f;
  float ip = 0.0f;
  int sc = 0;
  if (tid < 128) ip = Iext[(size_t)(b0 + bl) * NH + j0 + jl];
  __syncthreads();  // WL ready

  for (int t = 0; t < T_STEPS; ++t) {
    const int par = t & 1;
    u64* sbase = sync + (size_t)par * B_SZ * NJG;

    if (tid < 128) {
      // ---- state update (op order matches reference exactly) ----
      const float I = ip + psc;
      A1 *= D1; A2 *= D2;
      v = v + ((-60.0f - v) / 20.0f + (I + A1 + A2) / 2.0f);
      const bool inref = rf > 0.0f;
      if (inref) v = -60.0f;
      const bool spike = (!inref) && (v >= -45.0f);
      if (spike) { v = -60.0f; A1 += 1.0f; A2 += -2.0f; rf = 2.0f; sc++; }
      else       { rf = fmaxf(rf - 1.0f, 0.0f); }

      // ---- publish: word (b0+bb, chunk=jg), payload = 32 j-bits of one batch ----
      const u64 bal = __ballot(spike);  // wave = 2 batches x 32 j
      if ((ln & 31) == 0) {
        const int bb = b0 + wv * 2 + (ln >> 5);
        const unsigned payload = (ln >= 32) ? (unsigned)(bal >> 32) : (unsigned)bal;
        st64_agent(&sbase[(size_t)bb * NJG + jg],
                   (u64)payload | ((u64)(unsigned)(t + 1) << 32));
      }
      __builtin_amdgcn_sched_barrier(0);  // publish stays above the poll

      // ---- poll: 1 word per thread (batch b0+bl, chunk jl), all 128 in parallel ----
      u64 val;
      {
        const u64* gp = &sbase[(size_t)(b0 + bl) * NJG + jl];
        const unsigned want = (unsigned)(t + 1);
        do { val = ld64_agent(gp); } while ((unsigned)(val >> 32) != want);
      }
      unsigned myw = (unsigned)val;

      // ---- compact bitmap -> index list (2 batches per wave, 32-lane segments) ----
      int inc = __popc(myw);
#pragma unroll
      for (int d = 1; d < 32; d <<= 1) {
        const int y = __shfl_up(inc, d);
        if ((ln & 31) >= d) inc += y;     // segmented inclusive scan
      }
      if ((ln & 31) == 15) scnt[bl][0] = inc;   // cntA: chunks 0-15 = i<512
      if ((ln & 31) == 31) scnt[bl][1] = inc;   // cnt
      int off = inc - __popc(myw);              // exclusive offset
      const int base = jl * 32;                 // chunk jl covers i = 32*jl + bit
      while (myw) {
        const int bit = __builtin_ctz(myw);
        myw &= myw - 1;
        slist[bl][off++] = (unsigned short)(base + bit);
      }
    }
    __syncthreads();  // B1: slist/scnt ready

    // prefetch next step's I_ext; vmcnt drain lands at B2, hidden under the
    // LDS-only gather (gather touches no vmem)
    float ipn = ip;
    if (tid < 128) {
      const int tn2 = (t + 1 < T_STEPS) ? t + 1 : t;
      ipn = Iext[((size_t)tn2 * B_SZ + b0 + bl) * NH + j0 + jl];
    }

    // ---- LDS gather, 8-deep MLP, adds applied in list order ----
    // lo half (tid<128): entries [0,cntA) = i<512; hi half: [cntA,cnt).
    float s = 0.0f;
    {
      const int k0 = (tid < 128) ? 0 : scnt[bl][0];
      const int k1 = (tid < 128) ? scnt[bl][0] : scnt[bl][1];
      int k = k0;
      for (; k + 8 <= k1; k += 8) {
        float w8[8];
#pragma unroll
        for (int m = 0; m < 8; ++m) w8[m] = WL[slist[bl][k + m]][jl];
#pragma unroll
        for (int m = 0; m < 8; ++m) s += w8[m];   // in-order adds
      }
      for (; k < k1; ++k) s += WL[slist[bl][k]][jl];
    }
    if (tid >= 128) psumB[tid - 128] = s;
    __syncthreads();  // B2: hi-half sums ready; also guards slist/scnt overwrite

    if (tid < 128) {
      const float rec = s + psumB[tid];   // lo + hi, same association as R6's A+B
      h = D2 * h + rec;
      psc = D2 * psc + h;                 // psc uses updated h (matches reference)
      ip = ipn;
    }
  }

  if (tid < 128) rate[(size_t)(b0 + bl) * NH + j0 + jl] = (float)sc / 1000.0f;
}

// ---------------- kernel 3: out = rate @ W_out^T (unchanged) ----------------
__global__ __launch_bounds__(256) void out_gemv(const float* __restrict__ rate,
                                                const float* __restrict__ Wout,
                                                float* __restrict__ out) {
  __shared__ float rs[NH];
  const int b = blockIdx.x, tid = threadIdx.x;
  for (int i = tid; i < NH; i += 256) rs[i] = rate[(size_t)b * NH + i];
  __syncthreads();
  const float* wr = Wout + (size_t)tid * NH;
  float s = 0.0f;
  for (int hh = 0; hh < NH; hh += 4) {
    float4 w4 = *(const float4*)&wr[hh];
    s += rs[hh] * w4.x + rs[hh + 1] * w4.y + rs[hh + 2] * w4.z + rs[hh + 3] * w4.w;
  }
  out[(size_t)b * NO + tid] = s;
}

// ---------------- launch ----------------
extern "C" void kernel_launch(void* const* d_in, const int* in_sizes, int n_in,
                              void* d_out, int out_size, void* d_ws, size_t ws_size,
                              hipStream_t stream) {
  const float* x    = (const float*)d_in[0];
  const float* Win  = (const float*)d_in[1];
  const float* Wrec = (const float*)d_in[2];
  const float* Wout = (const float*)d_in[3];
  float* out = (float*)d_out;

  char* ws = (char*)d_ws;
  float* Iext = (float*)(ws + OFF_IEXT);
  float* rate = (float*)(ws + OFF_RATE);
  u64*   sync = (u64*)(ws + OFF_SYNC);
  // No memset needed: 0xAA poison tag (0xAAAAAAAA) never equals t+1 <= 1000;
  // every block publishes before it polls; deterministic rerun makes the
  // prior-run t=998 tag collision benign (same payload).

  gemm_in<<<dim3((T_STEPS * B_SZ) / GBM, NH / GBN), dim3(256), 0, stream>>>(x, Win, Iext);
  scan_rsnn<<<dim3(NBLK), dim3(256), 0, stream>>>(Iext, Wrec, rate, sync);
  out_gemv<<<dim3(B_SZ), dim3(256), 0, stream>>>(rate, Wout, out);
}